// Round 1
// baseline (609.631 us; speedup 1.0000x reference)
//
#include <hip/hip_runtime.h>

#define N_NODES  50000
#define N_EDGES  800000
#define N_GRAPHS 2000
#define N_PAIRS  4096
#define IN_CH    64
#define EMB      128
#define HID      256

// ---------------- transpose: Wt[k][j] = W[j][k], W is [R][K] row-major ----------------
__global__ void k_transpose(const float* __restrict__ in, float* __restrict__ out, int R, int K) {
    int tid = blockIdx.x * blockDim.x + threadIdx.x;
    if (tid >= R * K) return;
    int j = tid / K, k = tid % K;
    out[k * R + j] = in[tid];
}

// ---------------- degree count (in-degree by col) ----------------
__global__ void k_deg(const int* __restrict__ col, int* __restrict__ deg) {
    int e = blockIdx.x * blockDim.x + threadIdx.x;
    if (e < N_EDGES) atomicAdd(&deg[col[e]], 1);
}

// ---------------- single-block exclusive scan (int) ----------------
__global__ void k_scan_excl(const int* __restrict__ in, int* __restrict__ out, int n, int write_total) {
    __shared__ int wsum[16];
    __shared__ int carry_s;
    int t = threadIdx.x;
    int lane = t & 63, wid = t >> 6;
    if (t == 0) carry_s = 0;
    __syncthreads();
    for (int base = 0; base < n; base += 1024) {
        int i = base + t;
        int v = (i < n) ? in[i] : 0;
        int x = v;
        #pragma unroll
        for (int off = 1; off < 64; off <<= 1) {
            int y = __shfl_up(x, off, 64);
            if (lane >= off) x += y;
        }
        if (lane == 63) wsum[wid] = x;
        __syncthreads();
        int wexcl = 0;
        for (int w = 0; w < wid; w++) wexcl += wsum[w];
        int carry = carry_s;
        if (i < n) out[i] = x - v + wexcl + carry;
        __syncthreads();
        if (t == 1023) carry_s = carry + wexcl + x;
        __syncthreads();
    }
    if (write_total && t == 0) out[n] = carry_s;
}

// ---------------- dinv / invdeg ----------------
__global__ void k_dinv(const int* __restrict__ deg, float* __restrict__ dinv, float* __restrict__ invdeg) {
    int n = blockIdx.x * blockDim.x + threadIdx.x;
    if (n >= N_NODES) return;
    float d = (float)(deg[n] + 1);   // +1 self loop
    dinv[n]   = 1.0f / sqrtf(d);
    invdeg[n] = 1.0f / d;
}

// ---------------- CSR fill (by col) ----------------
__global__ void k_fill(const int* __restrict__ row, const int* __restrict__ col,
                       const int* __restrict__ off, int* __restrict__ cursor,
                       int* __restrict__ csr_row) {
    int e = blockIdx.x * blockDim.x + threadIdx.x;
    if (e >= N_EDGES) return;
    int c = col[e];
    int pos = atomicAdd(&cursor[c], 1);
    csr_row[off[c] + pos] = row[e];
}

// ---------------- pull-based normalized aggregation ----------------
template <int C, bool RELU, bool BIAS>
__global__ void k_gather(const float* __restrict__ h, const int* __restrict__ csr_row,
                         const int* __restrict__ off, const float* __restrict__ dinv,
                         const float* __restrict__ invdeg, const float* __restrict__ bias,
                         float* __restrict__ out) {
    constexpr int NPB = 256 / C;
    int local = threadIdx.x / C;
    int ch    = threadIdx.x % C;
    int n = blockIdx.x * NPB + local;
    if (n >= N_NODES) return;
    int s = off[n], e = off[n + 1];
    float acc = 0.f;
    for (int i = s; i < e; ++i) {
        int r = csr_row[i];
        acc += h[r * C + ch] * dinv[r];
    }
    acc = acc * dinv[n] + h[n * C + ch] * invdeg[n];
    if (BIAS) acc += bias[ch];
    if (RELU) acc = fmaxf(acc, 0.f);
    out[n * C + ch] = acc;
}

// ---------------- simple row-strip GEMM: out[r][c] = A[r][:] . Wt[:][c] ----------------
template <int K, bool RELU, bool BIAS>
__global__ void k_gemm(const float* __restrict__ A, const float* __restrict__ Wt,
                       const float* __restrict__ bias, float* __restrict__ out) {
    int c = threadIdx.x;             // 0..127
    int row0 = blockIdx.x * 8;
    float acc[8] = {0, 0, 0, 0, 0, 0, 0, 0};
    for (int k = 0; k < K; k += 4) {
        float w0 = Wt[(k + 0) * EMB + c];
        float w1 = Wt[(k + 1) * EMB + c];
        float w2 = Wt[(k + 2) * EMB + c];
        float w3 = Wt[(k + 3) * EMB + c];
        #pragma unroll
        for (int r = 0; r < 8; ++r) {
            const float4 a = *reinterpret_cast<const float4*>(&A[(row0 + r) * K + k]);
            acc[r] = fmaf(a.x, w0, fmaf(a.y, w1, fmaf(a.z, w2, fmaf(a.w, w3, acc[r]))));
        }
    }
    #pragma unroll
    for (int r = 0; r < 8; ++r) {
        float v = acc[r];
        if (BIAS) v += bias[c];
        if (RELU) v = fmaxf(v, 0.f);
        out[(row0 + r) * EMB + c] = v;
    }
}

// ---------------- graph readout (scatter mean, part 1: sums) ----------------
__global__ void k_readout(const float* __restrict__ h2, const int* __restrict__ batch,
                          float* __restrict__ gsum, int* __restrict__ cnt) {
    int idx = blockIdx.x * blockDim.x + threadIdx.x;
    if (idx >= N_NODES * EMB) return;
    int n = idx >> 7, ch = idx & 127;
    int g = batch[n];
    atomicAdd(&gsum[g * EMB + ch], h2[idx]);
    if (ch == 0) atomicAdd(&cnt[n >= 0 ? g : 0], 1);
}

// ---------------- divide by count ----------------
__global__ void k_gdiv(float* __restrict__ gsum, const int* __restrict__ cnt) {
    int idx = blockIdx.x * blockDim.x + threadIdx.x;
    if (idx >= N_GRAPHS * EMB) return;
    int g = idx >> 7;
    int c = cnt[g];
    float denom = (float)(c > 1 ? c : 1);
    gsum[idx] = gsum[idx] / denom;
}

// ---------------- presence bitmap for digitize-rank ----------------
__global__ void k_present(const int* __restrict__ dd, int* __restrict__ present) {
    int i = blockIdx.x * blockDim.x + threadIdx.x;
    if (i < 2 * N_PAIRS) present[dd[i]] = 1;
}

// ---------------- pair MLP: out[p] = w2 . relu(W1 . [e0;e1] + b1) + b2 ----------------
__global__ void k_mlp(const float* __restrict__ gemb, const int* __restrict__ dd,
                      const int* __restrict__ rankx,
                      const float* __restrict__ w1, const float* __restrict__ b1,
                      const float* __restrict__ w2, const float* __restrict__ b2,
                      float* __restrict__ out) {
    __shared__ __align__(16) float pv[2 * EMB];
    __shared__ float red[HID];
    int p = blockIdx.x, t = threadIdx.x;
    int ga = rankx[dd[p]];
    int gb = rankx[dd[N_PAIRS + p]];
    if (t < EMB) pv[t] = gemb[ga * EMB + t];
    else         pv[t] = gemb[gb * EMB + (t - EMB)];
    __syncthreads();
    float acc = b1[t];
    const float4* wrow = reinterpret_cast<const float4*>(&w1[t * 2 * EMB]);
    #pragma unroll 8
    for (int k = 0; k < (2 * EMB) / 4; ++k) {
        float4 w = wrow[k];
        const float4 x = *reinterpret_cast<const float4*>(&pv[k * 4]);
        acc = fmaf(x.x, w.x, fmaf(x.y, w.y, fmaf(x.z, w.z, fmaf(x.w, w.w, acc))));
    }
    float contrib = fmaxf(acc, 0.f) * w2[t];
    red[t] = contrib;
    __syncthreads();
    for (int s = HID / 2; s > 0; s >>= 1) {
        if (t < s) red[t] += red[t + s];
        __syncthreads();
    }
    if (t == 0) out[p] = red[0] + b2[0];
}

extern "C" void kernel_launch(void* const* d_in, const int* in_sizes, int n_in,
                              void* d_out, int out_size, void* d_ws, size_t ws_size,
                              hipStream_t stream) {
    const float* x        = (const float*)d_in[0];
    const int*   ei       = (const int*)d_in[1];      // [2, E]
    const int*   batch    = (const int*)d_in[2];
    const int*   dd       = (const int*)d_in[3];      // [2, P]
    const float* conv1_w  = (const float*)d_in[4];
    const float* conv1_b  = (const float*)d_in[5];
    const float* conv2_w  = (const float*)d_in[6];
    const float* conv2_b  = (const float*)d_in[7];
    const float* reg1_w   = (const float*)d_in[8];
    const float* reg1_b   = (const float*)d_in[9];
    const float* reg2_w   = (const float*)d_in[10];
    const float* reg2_b   = (const float*)d_in[11];
    float* outp = (float*)d_out;

    const int* ei_row = ei;
    const int* ei_col = ei + N_EDGES;

    // ---- workspace layout ----
    char* ws = (char*)d_ws;
    size_t o = 0;
    auto alloc = [&](size_t bytes) -> void* {
        void* p = ws + o;
        o = (o + bytes + 255) & ~(size_t)255;
        return p;
    };
    // zeroed region (contiguous)
    size_t zero_start = o;
    int*   deg     = (int*)alloc(N_NODES * 4);
    int*   cursor  = (int*)alloc(N_NODES * 4);
    int*   cnt     = (int*)alloc(N_GRAPHS * 4);
    int*   present = (int*)alloc(N_GRAPHS * 4);
    float* gsum    = (float*)alloc(N_GRAPHS * EMB * 4);
    size_t zero_bytes = o - zero_start;
    // rest
    int*   off     = (int*)alloc((N_NODES + 1) * 4);
    float* dinv    = (float*)alloc(N_NODES * 4);
    float* invdeg  = (float*)alloc(N_NODES * 4);
    int*   csr_row = (int*)alloc(N_EDGES * 4);
    int*   rankx   = (int*)alloc(N_GRAPHS * 4);
    float* Wt1     = (float*)alloc(IN_CH * EMB * 4);
    float* Wt2     = (float*)alloc(EMB * EMB * 4);
    float* aggx    = (float*)alloc((size_t)N_NODES * IN_CH * 4);
    float* h1      = (float*)alloc((size_t)N_NODES * EMB * 4);
    float* t2      = (float*)alloc((size_t)N_NODES * EMB * 4);
    float* h2      = h1;   // h1 is dead after GEMM2 reads it; alias

    (void)ws_size; (void)in_sizes; (void)n_in; (void)out_size;

    hipMemsetAsync(ws + zero_start, 0, zero_bytes, stream);

    // weight transposes
    k_transpose<<<(EMB * IN_CH + 255) / 256, 256, 0, stream>>>(conv1_w, Wt1, EMB, IN_CH);
    k_transpose<<<(EMB * EMB + 255) / 256, 256, 0, stream>>>(conv2_w, Wt2, EMB, EMB);

    // CSR build
    k_deg<<<N_EDGES / 256, 256, 0, stream>>>(ei_col, deg);
    k_scan_excl<<<1, 1024, 0, stream>>>(deg, off, N_NODES, 1);
    k_dinv<<<(N_NODES + 255) / 256, 256, 0, stream>>>(deg, dinv, invdeg);
    k_fill<<<N_EDGES / 256, 256, 0, stream>>>(ei_row, ei_col, off, cursor, csr_row);

    // conv1: aggregate in input space (linearity), then GEMM + bias + relu
    k_gather<IN_CH, false, false><<<N_NODES / (256 / IN_CH), 256, 0, stream>>>(
        x, csr_row, off, dinv, invdeg, nullptr, aggx);
    k_gemm<IN_CH, true, true><<<N_NODES / 8, EMB, 0, stream>>>(aggx, Wt1, conv1_b, h1);

    // conv2: GEMM first, then aggregate + bias + relu
    k_gemm<EMB, false, false><<<N_NODES / 8, EMB, 0, stream>>>(h1, Wt2, nullptr, t2);
    k_gather<EMB, true, true><<<N_NODES / (256 / EMB), 256, 0, stream>>>(
        t2, csr_row, off, dinv, invdeg, conv2_b, h2);

    // readout: scatter-mean
    k_readout<<<(N_NODES * EMB) / 256, 256, 0, stream>>>(h2, batch, gsum, cnt);
    k_gdiv<<<(N_GRAPHS * EMB + 255) / 256, 256, 0, stream>>>(gsum, cnt);

    // digitize-rank
    k_present<<<(2 * N_PAIRS) / 256, 256, 0, stream>>>(dd, present);
    k_scan_excl<<<1, 1024, 0, stream>>>(present, rankx, N_GRAPHS, 0);

    // pair MLP
    k_mlp<<<N_PAIRS, HID, 0, stream>>>(gsum, dd, rankx, reg1_w, reg1_b, reg2_w, reg2_b, outp);
}

// Round 2
// 310.652 us; speedup vs baseline: 1.9624x; 1.9624x over previous
//
#include <hip/hip_runtime.h>

#define N_NODES  50000
#define N_EDGES  800000
#define N_GRAPHS 2000
#define N_PAIRS  4096
#define IN_CH    64
#define EMB      128
#define HID      256
#define PPB      8

// ---------------- transpose: Wt[k][j] = W[j][k], W is [R][K] row-major ----------------
__global__ void k_transpose(const float* __restrict__ in, float* __restrict__ out, int R, int K) {
    int tid = blockIdx.x * blockDim.x + threadIdx.x;
    if (tid >= R * K) return;
    int j = tid / K, k = tid % K;
    out[k * R + j] = in[tid];
}

// ---------------- degree count (in-degree by col) ----------------
__global__ void k_deg(const int* __restrict__ col, int* __restrict__ deg) {
    int e = blockIdx.x * blockDim.x + threadIdx.x;
    if (e < N_EDGES) atomicAdd(&deg[col[e]], 1);
}

// ---------------- multi-block exclusive scan ----------------
__device__ inline int wave_incl_scan(int x, int lane) {
    #pragma unroll
    for (int off = 1; off < 64; off <<= 1) {
        int y = __shfl_up(x, off, 64);
        if (lane >= off) x += y;
    }
    return x;
}

__global__ void k_scan1(const int* __restrict__ in, int* __restrict__ part, int n) {
    __shared__ int ws[4];
    int i = blockIdx.x * 256 + threadIdx.x;
    int lane = threadIdx.x & 63, wid = threadIdx.x >> 6;
    int v = (i < n) ? in[i] : 0;
    int x = wave_incl_scan(v, lane);
    if (lane == 63) ws[wid] = x;
    __syncthreads();
    if (threadIdx.x == 0) part[blockIdx.x] = ws[0] + ws[1] + ws[2] + ws[3];
}

__global__ void k_scan2(int* __restrict__ part, int nb) {   // single block, nb <= 256
    __shared__ int ws[4];
    int t = threadIdx.x, lane = t & 63, wid = t >> 6;
    int v = (t < nb) ? part[t] : 0;
    int x = wave_incl_scan(v, lane);
    if (lane == 63) ws[wid] = x;
    __syncthreads();
    int add = 0;
    for (int w = 0; w < wid; ++w) add += ws[w];
    if (t < nb) part[t] = x - v + add;   // exclusive
}

__global__ void k_scan3(const int* __restrict__ in, const int* __restrict__ part,
                        int* __restrict__ out, int n) {
    __shared__ int ws[4];
    int i = blockIdx.x * 256 + threadIdx.x;
    int lane = threadIdx.x & 63, wid = threadIdx.x >> 6;
    int v = (i < n) ? in[i] : 0;
    int x = wave_incl_scan(v, lane);
    if (lane == 63) ws[wid] = x;
    __syncthreads();
    int add = part[blockIdx.x];
    for (int w = 0; w < wid; ++w) add += ws[w];
    if (i < n) out[i] = x - v + add;
}

// ---------------- dinv; also writes off[N_NODES] sentinel ----------------
__global__ void k_dinv(const int* __restrict__ deg, float* __restrict__ dinv, int* __restrict__ off) {
    int n = blockIdx.x * blockDim.x + threadIdx.x;
    if (n == 0) off[N_NODES] = N_EDGES;
    if (n >= N_NODES) return;
    float d = (float)(deg[n] + 1);   // +1 self loop
    dinv[n] = 1.0f / sqrtf(d);
}

// ---------------- CSR fill (by col) ----------------
__global__ void k_fill(const int* __restrict__ row, const int* __restrict__ col,
                       const int* __restrict__ off, int* __restrict__ cursor,
                       int* __restrict__ csr_row) {
    int e = blockIdx.x * blockDim.x + threadIdx.x;
    if (e >= N_EDGES) return;
    int c = col[e];
    int pos = atomicAdd(&cursor[c], 1);
    csr_row[off[c] + pos] = row[e];
}

// ---------------- xs = x * dinv[row] (float4) ----------------
__global__ void k_scale(const float4* __restrict__ x, const float* __restrict__ dinv,
                        float4* __restrict__ xs) {
    int i = blockIdx.x * 256 + threadIdx.x;
    if (i >= N_NODES * (IN_CH / 4)) return;
    int n = i / (IN_CH / 4);
    float d = dinv[n];
    float4 v = x[i];
    v.x *= d; v.y *= d; v.z *= d; v.w *= d;
    xs[i] = v;
}

// ---------------- pull aggregation: out[n] = dinv[n]*(sum_{r in N(n)} hs[r] + hs[n]) ----------------
template <int C, bool RELU, bool BIAS>
__global__ void k_gather4(const float4* __restrict__ hs, const int* __restrict__ csr_row,
                          const int* __restrict__ off, const float* __restrict__ dinv,
                          const float* __restrict__ bias, float4* __restrict__ out) {
    constexpr int L = C / 4;          // float4 lanes per node
    constexpr int NPB = 256 / L;
    int local = threadIdx.x / L;
    int c4 = threadIdx.x % L;
    int n = blockIdx.x * NPB + local;
    if (n >= N_NODES) return;
    int s = off[n], e = off[n + 1];
    float4 acc = hs[n * L + c4];      // self term
    int i = s;
    for (; i + 4 <= e; i += 4) {
        int r0 = csr_row[i + 0], r1 = csr_row[i + 1];
        int r2 = csr_row[i + 2], r3 = csr_row[i + 3];
        float4 a0 = hs[r0 * L + c4];
        float4 a1 = hs[r1 * L + c4];
        float4 a2 = hs[r2 * L + c4];
        float4 a3 = hs[r3 * L + c4];
        acc.x += (a0.x + a1.x) + (a2.x + a3.x);
        acc.y += (a0.y + a1.y) + (a2.y + a3.y);
        acc.z += (a0.z + a1.z) + (a2.z + a3.z);
        acc.w += (a0.w + a1.w) + (a2.w + a3.w);
    }
    for (; i < e; ++i) {
        int r = csr_row[i];
        float4 a = hs[r * L + c4];
        acc.x += a.x; acc.y += a.y; acc.z += a.z; acc.w += a.w;
    }
    float dn = dinv[n];
    acc.x *= dn; acc.y *= dn; acc.z *= dn; acc.w *= dn;
    if (BIAS) {
        float4 b = reinterpret_cast<const float4*>(bias)[c4];
        acc.x += b.x; acc.y += b.y; acc.z += b.z; acc.w += b.w;
    }
    if (RELU) {
        acc.x = fmaxf(acc.x, 0.f); acc.y = fmaxf(acc.y, 0.f);
        acc.z = fmaxf(acc.z, 0.f); acc.w = fmaxf(acc.w, 0.f);
    }
    out[n * L + c4] = acc;
}

// ---------------- row-strip GEMM: out[r][c] = A[r][:] . Wt[:][c] ----------------
template <int K, bool RELU, bool BIAS, bool SCALE>
__global__ void k_gemm(const float* __restrict__ A, const float* __restrict__ Wt,
                       const float* __restrict__ bias, const float* __restrict__ rowscale,
                       float* __restrict__ out) {
    int c = threadIdx.x;             // 0..127
    int row0 = blockIdx.x * 8;
    float acc[8] = {0, 0, 0, 0, 0, 0, 0, 0};
    for (int k = 0; k < K; k += 4) {
        float w0 = Wt[(k + 0) * EMB + c];
        float w1 = Wt[(k + 1) * EMB + c];
        float w2 = Wt[(k + 2) * EMB + c];
        float w3 = Wt[(k + 3) * EMB + c];
        #pragma unroll
        for (int r = 0; r < 8; ++r) {
            const float4 a = *reinterpret_cast<const float4*>(&A[(row0 + r) * K + k]);
            acc[r] = fmaf(a.x, w0, fmaf(a.y, w1, fmaf(a.z, w2, fmaf(a.w, w3, acc[r]))));
        }
    }
    #pragma unroll
    for (int r = 0; r < 8; ++r) {
        float v = acc[r];
        if (SCALE) v *= rowscale[row0 + r];
        if (BIAS) v += bias[c];
        if (RELU) v = fmaxf(v, 0.f);
        out[(row0 + r) * EMB + c] = v;
    }
}

// ---------------- readout: batch is SORTED -> run-based segmented sum ----------------
__global__ void k_readout2(const float* __restrict__ h2, const int* __restrict__ batch,
                           float* __restrict__ gsum) {
    int n0 = blockIdx.x * 16;
    int ch = threadIdx.x;            // 0..127
    int g = batch[n0];
    float acc = 0.f;
    for (int n = n0; n < n0 + 16; ++n) {
        int gn = batch[n];
        if (gn != g) {
            atomicAdd(&gsum[g * EMB + ch], acc);
            acc = 0.f; g = gn;
        }
        acc += h2[n * EMB + ch];
    }
    atomicAdd(&gsum[g * EMB + ch], acc);
}

__global__ void k_cnt(const int* __restrict__ batch, int* __restrict__ cnt) {
    int n = blockIdx.x * 256 + threadIdx.x;
    if (n < N_NODES) atomicAdd(&cnt[batch[n]], 1);
}

__global__ void k_gdiv(float* __restrict__ gsum, const int* __restrict__ cnt) {
    int idx = blockIdx.x * blockDim.x + threadIdx.x;
    if (idx >= N_GRAPHS * EMB) return;
    int g = idx >> 7;
    int c = cnt[g];
    float denom = (float)(c > 1 ? c : 1);
    gsum[idx] = gsum[idx] / denom;
}

// ---------------- presence bitmap for digitize-rank ----------------
__global__ void k_present(const int* __restrict__ dd, int* __restrict__ present) {
    int i = blockIdx.x * blockDim.x + threadIdx.x;
    if (i < 2 * N_PAIRS) present[dd[i]] = 1;
}

// ---------------- pair MLP, 8 pairs/block (W1-row reuse x8) ----------------
__global__ void k_mlp8(const float* __restrict__ gemb, const int* __restrict__ dd,
                       const int* __restrict__ rankx,
                       const float* __restrict__ w1, const float* __restrict__ b1,
                       const float* __restrict__ w2, const float* __restrict__ b2,
                       float* __restrict__ out) {
    __shared__ __align__(16) float pv[PPB][2 * EMB];
    __shared__ float wpart[4][PPB];
    int p0 = blockIdx.x * PPB;
    int t = threadIdx.x;             // 0..255
    int lane = t & 63, wid = t >> 6;
    #pragma unroll
    for (int j = 0; j < PPB; ++j) {
        int p = p0 + j;
        int ga = rankx[dd[p]];
        int gb = rankx[dd[N_PAIRS + p]];
        if (t < EMB) pv[j][t] = gemb[ga * EMB + t];
        else         pv[j][t] = gemb[gb * EMB + (t - EMB)];
    }
    __syncthreads();
    float acc[PPB];
    float bv = b1[t];
    #pragma unroll
    for (int j = 0; j < PPB; ++j) acc[j] = bv;
    const float4* wrow = reinterpret_cast<const float4*>(&w1[t * 2 * EMB]);
    for (int k = 0; k < (2 * EMB) / 4; ++k) {
        float4 w = wrow[k];
        #pragma unroll
        for (int j = 0; j < PPB; ++j) {
            const float4 xv = *reinterpret_cast<const float4*>(&pv[j][k * 4]);
            acc[j] = fmaf(xv.x, w.x, fmaf(xv.y, w.y, fmaf(xv.z, w.z, fmaf(xv.w, w.w, acc[j]))));
        }
    }
    float w2t = w2[t];
    float contrib[PPB];
    #pragma unroll
    for (int j = 0; j < PPB; ++j) contrib[j] = fmaxf(acc[j], 0.f) * w2t;
    #pragma unroll
    for (int off = 32; off > 0; off >>= 1) {
        #pragma unroll
        for (int j = 0; j < PPB; ++j) contrib[j] += __shfl_down(contrib[j], off, 64);
    }
    if (lane == 0) {
        #pragma unroll
        for (int j = 0; j < PPB; ++j) wpart[wid][j] = contrib[j];
    }
    __syncthreads();
    if (t < PPB) {
        out[p0 + t] = wpart[0][t] + wpart[1][t] + wpart[2][t] + wpart[3][t] + b2[0];
    }
}

extern "C" void kernel_launch(void* const* d_in, const int* in_sizes, int n_in,
                              void* d_out, int out_size, void* d_ws, size_t ws_size,
                              hipStream_t stream) {
    const float* x        = (const float*)d_in[0];
    const int*   ei       = (const int*)d_in[1];      // [2, E]
    const int*   batch    = (const int*)d_in[2];
    const int*   dd       = (const int*)d_in[3];      // [2, P]
    const float* conv1_w  = (const float*)d_in[4];
    const float* conv1_b  = (const float*)d_in[5];
    const float* conv2_w  = (const float*)d_in[6];
    const float* conv2_b  = (const float*)d_in[7];
    const float* reg1_w   = (const float*)d_in[8];
    const float* reg1_b   = (const float*)d_in[9];
    const float* reg2_w   = (const float*)d_in[10];
    const float* reg2_b   = (const float*)d_in[11];
    float* outp = (float*)d_out;

    const int* ei_row = ei;
    const int* ei_col = ei + N_EDGES;

    // ---- workspace layout ----
    char* ws = (char*)d_ws;
    size_t o = 0;
    auto alloc = [&](size_t bytes) -> void* {
        void* p = ws + o;
        o = (o + bytes + 255) & ~(size_t)255;
        return p;
    };
    size_t zero_start = o;
    int*   deg     = (int*)alloc(N_NODES * 4);
    int*   cursor  = (int*)alloc(N_NODES * 4);
    int*   cnt     = (int*)alloc(N_GRAPHS * 4);
    int*   present = (int*)alloc(N_GRAPHS * 4);
    float* gsum    = (float*)alloc(N_GRAPHS * EMB * 4);
    size_t zero_bytes = o - zero_start;
    int*   off     = (int*)alloc((N_NODES + 1) * 4);
    float* dinv    = (float*)alloc(N_NODES * 4);
    int*   part    = (int*)alloc(256 * 4);
    int*   csr_row = (int*)alloc(N_EDGES * 4);
    int*   rankx   = (int*)alloc(N_GRAPHS * 4);
    float* Wt1     = (float*)alloc(IN_CH * EMB * 4);
    float* Wt2     = (float*)alloc(EMB * EMB * 4);
    float* aggx    = (float*)alloc((size_t)N_NODES * IN_CH * 4);
    float* h1      = (float*)alloc((size_t)N_NODES * EMB * 4);
    float* t2      = (float*)alloc((size_t)N_NODES * EMB * 4);
    float* xs      = t2;   // xs (12.8MB) dead before GEMM2 writes t2
    float* h2      = h1;   // h1 dead after GEMM2 reads it

    (void)ws_size; (void)in_sizes; (void)n_in; (void)out_size;

    hipMemsetAsync(ws + zero_start, 0, zero_bytes, stream);

    // weight transposes
    k_transpose<<<(EMB * IN_CH + 255) / 256, 256, 0, stream>>>(conv1_w, Wt1, EMB, IN_CH);
    k_transpose<<<(EMB * EMB + 255) / 256, 256, 0, stream>>>(conv2_w, Wt2, EMB, EMB);

    // CSR build
    k_deg<<<N_EDGES / 256, 256, 0, stream>>>(ei_col, deg);
    {
        int nb = (N_NODES + 255) / 256;   // 196
        k_scan1<<<nb, 256, 0, stream>>>(deg, part, N_NODES);
        k_scan2<<<1, 256, 0, stream>>>(part, nb);
        k_scan3<<<nb, 256, 0, stream>>>(deg, part, off, N_NODES);
    }
    k_dinv<<<(N_NODES + 255) / 256, 256, 0, stream>>>(deg, dinv, off);
    k_fill<<<N_EDGES / 256, 256, 0, stream>>>(ei_row, ei_col, off, cursor, csr_row);

    // conv1: aggregate in input space (linearity), then GEMM + bias + relu
    k_scale<<<(N_NODES * (IN_CH / 4) + 255) / 256, 256, 0, stream>>>(
        (const float4*)x, dinv, (float4*)xs);
    k_gather4<IN_CH, false, false><<<(N_NODES + 15) / 16, 256, 0, stream>>>(
        (const float4*)xs, csr_row, off, dinv, nullptr, (float4*)aggx);
    k_gemm<IN_CH, true, true, false><<<N_NODES / 8, EMB, 0, stream>>>(
        aggx, Wt1, conv1_b, nullptr, h1);

    // conv2: GEMM (epilogue: scale rows by dinv), then aggregate + bias + relu
    k_gemm<EMB, false, false, true><<<N_NODES / 8, EMB, 0, stream>>>(
        h1, Wt2, nullptr, dinv, t2);
    k_gather4<EMB, true, true><<<(N_NODES + 7) / 8, 256, 0, stream>>>(
        (const float4*)t2, csr_row, off, dinv, conv2_b, (float4*)h2);

    // readout: run-based segmented sum (batch sorted)
    k_readout2<<<N_NODES / 16, EMB, 0, stream>>>(h2, batch, gsum);
    k_cnt<<<(N_NODES + 255) / 256, 256, 0, stream>>>(batch, cnt);
    k_gdiv<<<(N_GRAPHS * EMB + 255) / 256, 256, 0, stream>>>(gsum, cnt);

    // digitize-rank
    k_present<<<(2 * N_PAIRS) / 256, 256, 0, stream>>>(dd, present);
    {
        int nb = (N_GRAPHS + 255) / 256;  // 8
        k_scan1<<<nb, 256, 0, stream>>>(present, part, N_GRAPHS);
        k_scan2<<<1, 256, 0, stream>>>(part, nb);
        k_scan3<<<nb, 256, 0, stream>>>(present, part, rankx, N_GRAPHS);
    }

    // pair MLP
    k_mlp8<<<N_PAIRS / PPB, 256, 0, stream>>>(gsum, dd, rankx, reg1_w, reg1_b, reg2_w, reg2_b, outp);
}

// Round 3
// 300.124 us; speedup vs baseline: 2.0313x; 1.0351x over previous
//
#include <hip/hip_runtime.h>

#define N_NODES  50000
#define N_PAD    50048
#define N_EDGES  800000
#define N_GRAPHS 2000
#define N_PAIRS  4096
#define IN_CH    64
#define EMB      128
#define HID      256
#define PPB      8

// ---------------- both weight transposes in one kernel ----------------
__global__ void k_transpose2(const float* __restrict__ w1, const float* __restrict__ w2,
                             float* __restrict__ wt1, float* __restrict__ wt2) {
    int tid = blockIdx.x * 256 + threadIdx.x;
    if (tid < EMB * IN_CH) {
        int j = tid / IN_CH, k = tid % IN_CH;
        wt1[k * EMB + j] = w1[tid];
    } else {
        int t = tid - EMB * IN_CH;
        if (t < EMB * EMB) {
            int j = t / EMB, k = t % EMB;
            wt2[k * EMB + j] = w2[t];
        }
    }
}

// ---------------- edge in-degree + node graph-count, one kernel ----------------
__global__ void k_deg_cnt(const int* __restrict__ col, const int* __restrict__ batch,
                          int* __restrict__ deg, int* __restrict__ cnt) {
    int e = blockIdx.x * 256 + threadIdx.x;
    if (e < N_EDGES) atomicAdd(&deg[col[e]], 1);
    if (e < N_NODES) atomicAdd(&cnt[batch[e]], 1);
}

// ---------------- multi-block exclusive scan ----------------
__device__ inline int wave_incl_scan(int x, int lane) {
    #pragma unroll
    for (int off = 1; off < 64; off <<= 1) {
        int y = __shfl_up(x, off, 64);
        if (lane >= off) x += y;
    }
    return x;
}

__global__ void k_scan1(const int* __restrict__ in, int* __restrict__ part, int n) {
    __shared__ int ws[4];
    int i = blockIdx.x * 256 + threadIdx.x;
    int lane = threadIdx.x & 63, wid = threadIdx.x >> 6;
    int v = (i < n) ? in[i] : 0;
    int x = wave_incl_scan(v, lane);
    if (lane == 63) ws[wid] = x;
    __syncthreads();
    if (threadIdx.x == 0) part[blockIdx.x] = ws[0] + ws[1] + ws[2] + ws[3];
}

__global__ void k_scan2(int* __restrict__ part, int nb) {   // single block, nb <= 256
    __shared__ int ws[4];
    int t = threadIdx.x, lane = t & 63, wid = t >> 6;
    int v = (t < nb) ? part[t] : 0;
    int x = wave_incl_scan(v, lane);
    if (lane == 63) ws[wid] = x;
    __syncthreads();
    int add = 0;
    for (int w = 0; w < wid; ++w) add += ws[w];
    if (t < nb) part[t] = x - v + add;   // exclusive
}

// scan3 + dinv + off sentinel fused
__global__ void k_scan3d(const int* __restrict__ in, const int* __restrict__ part,
                         int* __restrict__ off, float* __restrict__ dinv) {
    __shared__ int ws[4];
    int i = blockIdx.x * 256 + threadIdx.x;
    int lane = threadIdx.x & 63, wid = threadIdx.x >> 6;
    int v = (i < N_NODES) ? in[i] : 0;
    int x = wave_incl_scan(v, lane);
    if (lane == 63) ws[wid] = x;
    __syncthreads();
    int add = part[blockIdx.x];
    for (int w = 0; w < wid; ++w) add += ws[w];
    if (i < N_NODES) {
        off[i] = x - v + add;
        dinv[i] = 1.0f / sqrtf((float)(v + 1));   // +1 self loop
    }
    if (i == 0) off[N_NODES] = N_EDGES;
}

// ---------------- CSR fill + xs = x*dinv scale, one kernel ----------------
__global__ void k_fill_scale(const int* __restrict__ row, const int* __restrict__ col,
                             const int* __restrict__ off, int* __restrict__ cursor,
                             int* __restrict__ csr_row,
                             const float4* __restrict__ x, const float* __restrict__ dinv,
                             float4* __restrict__ xs) {
    int idx = blockIdx.x * 256 + threadIdx.x;
    if (idx < N_EDGES) {
        int c = col[idx];
        int pos = atomicAdd(&cursor[c], 1);
        csr_row[off[c] + pos] = row[idx];
    } else {
        int i = idx - N_EDGES;           // exactly N_NODES*16 of these
        int n = i >> 4;
        float d = dinv[n];
        float4 v = x[i];
        v.x *= d; v.y *= d; v.z *= d; v.w *= d;
        xs[i] = v;
    }
}

// ---------------- pull aggregation (unroll 8): out[n] = dinv[n]*(sum hs[r] + hs[n]) ----------------
__device__ inline void f4add(float4& a, const float4 b) {
    a.x += b.x; a.y += b.y; a.z += b.z; a.w += b.w;
}

template <int C>
__global__ void k_gather8(const float4* __restrict__ hs, const int* __restrict__ csr_row,
                          const int* __restrict__ off, const float* __restrict__ dinv,
                          float4* __restrict__ out) {
    constexpr int L = C / 4;
    constexpr int NPB = 256 / L;
    int local = threadIdx.x / L;
    int c4 = threadIdx.x % L;
    int n = blockIdx.x * NPB + local;
    int s = off[n], e = off[n + 1];
    float4 acc = hs[n * L + c4];      // self term
    int i = s;
    for (; i + 8 <= e; i += 8) {
        int r0 = csr_row[i + 0], r1 = csr_row[i + 1], r2 = csr_row[i + 2], r3 = csr_row[i + 3];
        int r4 = csr_row[i + 4], r5 = csr_row[i + 5], r6 = csr_row[i + 6], r7 = csr_row[i + 7];
        float4 a0 = hs[r0 * L + c4], a1 = hs[r1 * L + c4];
        float4 a2 = hs[r2 * L + c4], a3 = hs[r3 * L + c4];
        float4 a4 = hs[r4 * L + c4], a5 = hs[r5 * L + c4];
        float4 a6 = hs[r6 * L + c4], a7 = hs[r7 * L + c4];
        f4add(a0, a1); f4add(a2, a3); f4add(a4, a5); f4add(a6, a7);
        f4add(a0, a2); f4add(a4, a6);
        f4add(a0, a4);
        f4add(acc, a0);
    }
    for (; i < e; ++i) {
        int r = csr_row[i];
        float4 a = hs[r * L + c4];
        f4add(acc, a);
    }
    float dn = dinv[n];
    acc.x *= dn; acc.y *= dn; acc.z *= dn; acc.w *= dn;
    out[n * L + c4] = acc;
}

// ---------------- gather128 + bias + relu + fused run-based readout into gsum ----------------
__global__ void k_gather_ro(const float4* __restrict__ t2, const int* __restrict__ csr_row,
                            const int* __restrict__ off, const float* __restrict__ dinv,
                            const float* __restrict__ bias, const int* __restrict__ batch,
                            float* __restrict__ gsum) {
    constexpr int L = EMB / 4;        // 32
    constexpr int NPB = 8;
    __shared__ __align__(16) float hb[NPB][EMB];
    __shared__ int bg[NPB];
    int local = threadIdx.x >> 5;
    int c4 = threadIdx.x & 31;
    int n0 = blockIdx.x * NPB;
    int n = n0 + local;
    if (threadIdx.x < NPB) bg[threadIdx.x] = batch[n0 + threadIdx.x];
    int s = off[n], e = off[n + 1];
    float4 acc = t2[n * L + c4];      // self term
    int i = s;
    for (; i + 8 <= e; i += 8) {
        int r0 = csr_row[i + 0], r1 = csr_row[i + 1], r2 = csr_row[i + 2], r3 = csr_row[i + 3];
        int r4 = csr_row[i + 4], r5 = csr_row[i + 5], r6 = csr_row[i + 6], r7 = csr_row[i + 7];
        float4 a0 = t2[r0 * L + c4], a1 = t2[r1 * L + c4];
        float4 a2 = t2[r2 * L + c4], a3 = t2[r3 * L + c4];
        float4 a4 = t2[r4 * L + c4], a5 = t2[r5 * L + c4];
        float4 a6 = t2[r6 * L + c4], a7 = t2[r7 * L + c4];
        f4add(a0, a1); f4add(a2, a3); f4add(a4, a5); f4add(a6, a7);
        f4add(a0, a2); f4add(a4, a6);
        f4add(a0, a4);
        f4add(acc, a0);
    }
    for (; i < e; ++i) {
        int r = csr_row[i];
        float4 a = t2[r * L + c4];
        f4add(acc, a);
    }
    float dn = dinv[n];
    float4 b = reinterpret_cast<const float4*>(bias)[c4];
    acc.x = fmaxf(fmaf(acc.x, dn, b.x), 0.f);
    acc.y = fmaxf(fmaf(acc.y, dn, b.y), 0.f);
    acc.z = fmaxf(fmaf(acc.z, dn, b.z), 0.f);
    acc.w = fmaxf(fmaf(acc.w, dn, b.w), 0.f);
    *reinterpret_cast<float4*>(&hb[local][c4 * 4]) = acc;
    __syncthreads();
    int ch = threadIdx.x;
    if (ch < EMB) {
        int g = bg[0];
        float a = 0.f;
        #pragma unroll
        for (int j = 0; j < NPB; ++j) {
            int gj = bg[j];
            if (gj != g) { atomicAdd(&gsum[g * EMB + ch], a); a = 0.f; g = gj; }
            a += hb[j][ch];
        }
        atomicAdd(&gsum[g * EMB + ch], a);
    }
}

// ---------------- reg-blocked GEMM: 64 rows x 128 cols per block, 8x4 per thread ----------------
template <int K, bool RELU, bool BIAS, bool POSTSCALE>
__global__ void k_gemmv2(const float* __restrict__ A, const float* __restrict__ Wt,
                         const float* __restrict__ bias, const float* __restrict__ rowscale,
                         float* __restrict__ out) {
    int t = threadIdx.x;
    int cq = (t & 31) << 2;          // col base 0..124
    int rg = t >> 5;                 // 0..7
    int row0 = blockIdx.x * 64 + rg * 8;
    float4 acc[8];
    #pragma unroll
    for (int r = 0; r < 8; ++r) acc[r] = make_float4(0.f, 0.f, 0.f, 0.f);
    for (int k = 0; k < K; k += 4) {
        float4 w0 = *reinterpret_cast<const float4*>(&Wt[(k + 0) * EMB + cq]);
        float4 w1 = *reinterpret_cast<const float4*>(&Wt[(k + 1) * EMB + cq]);
        float4 w2 = *reinterpret_cast<const float4*>(&Wt[(k + 2) * EMB + cq]);
        float4 w3 = *reinterpret_cast<const float4*>(&Wt[(k + 3) * EMB + cq]);
        #pragma unroll
        for (int r = 0; r < 8; ++r) {
            float4 a = *reinterpret_cast<const float4*>(&A[(size_t)(row0 + r) * K + k]);
            acc[r].x = fmaf(a.x, w0.x, fmaf(a.y, w1.x, fmaf(a.z, w2.x, fmaf(a.w, w3.x, acc[r].x))));
            acc[r].y = fmaf(a.x, w0.y, fmaf(a.y, w1.y, fmaf(a.z, w2.y, fmaf(a.w, w3.y, acc[r].y))));
            acc[r].z = fmaf(a.x, w0.z, fmaf(a.y, w1.z, fmaf(a.z, w2.z, fmaf(a.w, w3.z, acc[r].z))));
            acc[r].w = fmaf(a.x, w0.w, fmaf(a.y, w1.w, fmaf(a.z, w2.w, fmaf(a.w, w3.w, acc[r].w))));
        }
    }
    #pragma unroll
    for (int r = 0; r < 8; ++r) {
        int row = row0 + r;
        if (row < N_NODES) {
            float4 v = acc[r];
            if (BIAS) {
                float4 b = *reinterpret_cast<const float4*>(&bias[cq]);
                v.x += b.x; v.y += b.y; v.z += b.z; v.w += b.w;
            }
            if (RELU) {
                v.x = fmaxf(v.x, 0.f); v.y = fmaxf(v.y, 0.f);
                v.z = fmaxf(v.z, 0.f); v.w = fmaxf(v.w, 0.f);
            }
            if (POSTSCALE) {
                float sc = rowscale[row];
                v.x *= sc; v.y *= sc; v.z *= sc; v.w *= sc;
            }
            *reinterpret_cast<float4*>(&out[(size_t)row * EMB + cq]) = v;
        }
    }
}

// ---------------- digitize: presence + exclusive scan, one block ----------------
__global__ void k_digitize(const int* __restrict__ dd, int* __restrict__ rankx) {
    __shared__ int pres[N_GRAPHS];
    __shared__ int ws[4];
    __shared__ int carry;
    int t = threadIdx.x, lane = t & 63, wid = t >> 6;
    for (int i = t; i < N_GRAPHS; i += 256) pres[i] = 0;
    __syncthreads();
    for (int i = t; i < 2 * N_PAIRS; i += 256) pres[dd[i]] = 1;
    if (t == 0) carry = 0;
    __syncthreads();
    for (int base = 0; base < N_GRAPHS; base += 256) {
        int i = base + t;
        int v = (i < N_GRAPHS) ? pres[i] : 0;
        int x = wave_incl_scan(v, lane);
        if (lane == 63) ws[wid] = x;
        __syncthreads();
        int add = carry;
        for (int w = 0; w < wid; ++w) add += ws[w];
        if (i < N_GRAPHS) rankx[i] = x - v + add;
        __syncthreads();
        if (t == 255) carry = add + x;
        __syncthreads();
    }
}

// ---------------- pair MLP, 8 pairs/block, mean-division fused at load ----------------
__global__ void k_mlp8(const float* __restrict__ gemb, const int* __restrict__ cnt,
                       const int* __restrict__ dd, const int* __restrict__ rankx,
                       const float* __restrict__ w1, const float* __restrict__ b1,
                       const float* __restrict__ w2, const float* __restrict__ b2,
                       float* __restrict__ out) {
    __shared__ __align__(16) float pv[PPB][2 * EMB];
    __shared__ float wpart[4][PPB];
    int p0 = blockIdx.x * PPB;
    int t = threadIdx.x;             // 0..255
    int lane = t & 63, wid = t >> 6;
    #pragma unroll
    for (int j = 0; j < PPB; ++j) {
        int p = p0 + j;
        if (t < EMB) {
            int ga = rankx[dd[p]];
            int ca = cnt[ga];
            float ra = 1.0f / (float)(ca > 1 ? ca : 1);
            pv[j][t] = gemb[ga * EMB + t] * ra;
        } else {
            int gb = rankx[dd[N_PAIRS + p]];
            int cb = cnt[gb];
            float rb = 1.0f / (float)(cb > 1 ? cb : 1);
            pv[j][t] = gemb[gb * EMB + (t - EMB)] * rb;
        }
    }
    __syncthreads();
    float acc[PPB];
    float bv = b1[t];
    #pragma unroll
    for (int j = 0; j < PPB; ++j) acc[j] = bv;
    const float4* wrow = reinterpret_cast<const float4*>(&w1[t * 2 * EMB]);
    for (int k = 0; k < (2 * EMB) / 4; ++k) {
        float4 w = wrow[k];
        #pragma unroll
        for (int j = 0; j < PPB; ++j) {
            const float4 xv = *reinterpret_cast<const float4*>(&pv[j][k * 4]);
            acc[j] = fmaf(xv.x, w.x, fmaf(xv.y, w.y, fmaf(xv.z, w.z, fmaf(xv.w, w.w, acc[j]))));
        }
    }
    float w2t = w2[t];
    float contrib[PPB];
    #pragma unroll
    for (int j = 0; j < PPB; ++j) contrib[j] = fmaxf(acc[j], 0.f) * w2t;
    #pragma unroll
    for (int off = 32; off > 0; off >>= 1) {
        #pragma unroll
        for (int j = 0; j < PPB; ++j) contrib[j] += __shfl_down(contrib[j], off, 64);
    }
    if (lane == 0) {
        #pragma unroll
        for (int j = 0; j < PPB; ++j) wpart[wid][j] = contrib[j];
    }
    __syncthreads();
    if (t < PPB) {
        out[p0 + t] = wpart[0][t] + wpart[1][t] + wpart[2][t] + wpart[3][t] + b2[0];
    }
}

extern "C" void kernel_launch(void* const* d_in, const int* in_sizes, int n_in,
                              void* d_out, int out_size, void* d_ws, size_t ws_size,
                              hipStream_t stream) {
    const float* x        = (const float*)d_in[0];
    const int*   ei       = (const int*)d_in[1];      // [2, E]
    const int*   batch    = (const int*)d_in[2];
    const int*   dd       = (const int*)d_in[3];      // [2, P]
    const float* conv1_w  = (const float*)d_in[4];
    const float* conv1_b  = (const float*)d_in[5];
    const float* conv2_w  = (const float*)d_in[6];
    const float* conv2_b  = (const float*)d_in[7];
    const float* reg1_w   = (const float*)d_in[8];
    const float* reg1_b   = (const float*)d_in[9];
    const float* reg2_w   = (const float*)d_in[10];
    const float* reg2_b   = (const float*)d_in[11];
    float* outp = (float*)d_out;

    const int* ei_row = ei;
    const int* ei_col = ei + N_EDGES;

    // ---- workspace layout ----
    char* ws = (char*)d_ws;
    size_t o = 0;
    auto alloc = [&](size_t bytes) -> void* {
        void* p = ws + o;
        o = (o + bytes + 255) & ~(size_t)255;
        return p;
    };
    size_t zero_start = o;
    int*   deg     = (int*)alloc(N_NODES * 4);
    int*   cursor  = (int*)alloc(N_NODES * 4);
    int*   cnt     = (int*)alloc(N_GRAPHS * 4);
    float* gsum    = (float*)alloc(N_GRAPHS * EMB * 4);
    size_t zero_bytes = o - zero_start;
    int*   off     = (int*)alloc((N_NODES + 1) * 4);
    float* dinv    = (float*)alloc(N_NODES * 4);
    int*   part    = (int*)alloc(256 * 4);
    int*   csr_row = (int*)alloc(N_EDGES * 4);
    int*   rankx   = (int*)alloc(N_GRAPHS * 4);
    float* Wt1     = (float*)alloc(IN_CH * EMB * 4);
    float* Wt2     = (float*)alloc(EMB * EMB * 4);
    float* aggx    = (float*)alloc((size_t)N_PAD * IN_CH * 4);
    float* h1s     = (float*)alloc((size_t)N_PAD * EMB * 4);
    float* t2      = (float*)alloc((size_t)N_PAD * EMB * 4);
    float* xs      = t2;   // xs (12.8MB) dead before GEMM2 writes t2

    (void)ws_size; (void)in_sizes; (void)n_in; (void)out_size;

    hipMemsetAsync(ws + zero_start, 0, zero_bytes, stream);

    k_transpose2<<<(EMB * IN_CH + EMB * EMB + 255) / 256, 256, 0, stream>>>(conv1_w, conv2_w, Wt1, Wt2);
    k_deg_cnt<<<N_EDGES / 256, 256, 0, stream>>>(ei_col, batch, deg, cnt);
    {
        int nb = (N_NODES + 255) / 256;   // 196
        k_scan1<<<nb, 256, 0, stream>>>(deg, part, N_NODES);
        k_scan2<<<1, 256, 0, stream>>>(part, nb);
        k_scan3d<<<nb, 256, 0, stream>>>(deg, part, off, dinv);
    }
    k_fill_scale<<<(N_EDGES + N_NODES * (IN_CH / 4)) / 256, 256, 0, stream>>>(
        ei_row, ei_col, off, cursor, csr_row, (const float4*)x, dinv, (float4*)xs);

    // conv1: aggregate in 64-dim input space, then GEMM (+bias,relu, x dinv for conv2 prescale)
    k_gather8<IN_CH><<<N_NODES / (256 / (IN_CH / 4)), 256, 0, stream>>>(
        (const float4*)xs, csr_row, off, dinv, (float4*)aggx);
    k_gemmv2<IN_CH, true, true, true><<<N_PAD / 64, 256, 0, stream>>>(
        aggx, Wt1, conv1_b, dinv, h1s);

    // conv2: plain GEMM, then gather + bias + relu + fused readout
    k_gemmv2<EMB, false, false, false><<<N_PAD / 64, 256, 0, stream>>>(
        h1s, Wt2, nullptr, nullptr, t2);
    k_gather_ro<<<N_NODES / 8, 256, 0, stream>>>(
        (const float4*)t2, csr_row, off, dinv, conv2_b, batch, gsum);

    // digitize-rank (one block)
    k_digitize<<<1, 256, 0, stream>>>(dd, rankx);

    // pair MLP (mean division fused)
    k_mlp8<<<N_PAIRS / PPB, 256, 0, stream>>>(gsum, cnt, dd, rankx,
                                              reg1_w, reg1_b, reg2_w, reg2_b, outp);
}

// Round 4
// 272.103 us; speedup vs baseline: 2.2404x; 1.1030x over previous
//
#include <hip/hip_runtime.h>

#define N_NODES  50000
#define N_PAD    50048
#define N_EDGES  800000
#define N_GRAPHS 2000
#define N_PAIRS  4096
#define IN_CH    64
#define EMB      128
#define HID      256
#define PPB      16

// ---------------- pre pass: in-degree + per-edge rank + graph counts + weight transposes ----------------
__global__ void k_pre(const int* __restrict__ col, const int* __restrict__ batch,
                      const float* __restrict__ w1, const float* __restrict__ w2,
                      int* __restrict__ deg, int* __restrict__ pos_e, int* __restrict__ cnt,
                      float* __restrict__ wt1, float* __restrict__ wt2) {
    int e = blockIdx.x * 256 + threadIdx.x;
    if (e < N_EDGES) {
        int c = col[e];
        pos_e[e] = atomicAdd(&deg[c], 1);
    }
    if (e < N_NODES) atomicAdd(&cnt[batch[e]], 1);
    if (e < EMB * IN_CH) {
        int j = e / IN_CH, k = e % IN_CH;
        wt1[k * EMB + j] = w1[e];
    } else if (e < EMB * IN_CH + EMB * EMB) {
        int t = e - EMB * IN_CH;
        int j = t / EMB, k = t % EMB;
        wt2[k * EMB + j] = w2[t];
    }
}

// ---------------- multi-block exclusive scan ----------------
__device__ inline int wave_incl_scan(int x, int lane) {
    #pragma unroll
    for (int off = 1; off < 64; off <<= 1) {
        int y = __shfl_up(x, off, 64);
        if (lane >= off) x += y;
    }
    return x;
}

__global__ void k_scan1(const int* __restrict__ in, int* __restrict__ part, int n) {
    __shared__ int ws[4];
    int i = blockIdx.x * 256 + threadIdx.x;
    int lane = threadIdx.x & 63, wid = threadIdx.x >> 6;
    int v = (i < n) ? in[i] : 0;
    int x = wave_incl_scan(v, lane);
    if (lane == 63) ws[wid] = x;
    __syncthreads();
    if (threadIdx.x == 0) part[blockIdx.x] = ws[0] + ws[1] + ws[2] + ws[3];
}

__global__ void k_scan2(int* __restrict__ part, int nb) {   // single block, nb <= 256
    __shared__ int ws[4];
    int t = threadIdx.x, lane = t & 63, wid = t >> 6;
    int v = (t < nb) ? part[t] : 0;
    int x = wave_incl_scan(v, lane);
    if (lane == 63) ws[wid] = x;
    __syncthreads();
    int add = 0;
    for (int w = 0; w < wid; ++w) add += ws[w];
    if (t < nb) part[t] = x - v + add;   // exclusive
}

// scan3 + dinv + off sentinel fused
__global__ void k_scan3d(const int* __restrict__ in, const int* __restrict__ part,
                         int* __restrict__ off, float* __restrict__ dinv) {
    __shared__ int ws[4];
    int i = blockIdx.x * 256 + threadIdx.x;
    int lane = threadIdx.x & 63, wid = threadIdx.x >> 6;
    int v = (i < N_NODES) ? in[i] : 0;
    int x = wave_incl_scan(v, lane);
    if (lane == 63) ws[wid] = x;
    __syncthreads();
    int add = part[blockIdx.x];
    for (int w = 0; w < wid; ++w) add += ws[w];
    if (i < N_NODES) {
        off[i] = x - v + add;
        dinv[i] = 1.0f / sqrtf((float)(v + 1));   // +1 self loop
    }
    if (i == 0) off[N_NODES] = N_EDGES;
}

// ---------------- CSR fill (atomic-free) + xs = x*dinv scale, one kernel ----------------
__global__ void k_fill_scale(const int* __restrict__ row, const int* __restrict__ col,
                             const int* __restrict__ pos_e, const int* __restrict__ off,
                             int* __restrict__ csr_row,
                             const float4* __restrict__ x, const float* __restrict__ dinv,
                             float4* __restrict__ xs) {
    int idx = blockIdx.x * 256 + threadIdx.x;
    if (idx < N_EDGES) {
        int c = col[idx];
        int p = pos_e[idx];
        csr_row[off[c] + p] = row[idx];
    } else {
        int i = idx - N_EDGES;           // exactly N_NODES*16 of these
        int n = i >> 4;
        float d = dinv[n];
        float4 v = x[i];
        v.x *= d; v.y *= d; v.z *= d; v.w *= d;
        xs[i] = v;
    }
}

// ---------------- pull aggregation (unroll 8): out[n] = dinv[n]*(sum hs[r] + hs[n]) ----------------
__device__ inline void f4add(float4& a, const float4 b) {
    a.x += b.x; a.y += b.y; a.z += b.z; a.w += b.w;
}

template <int C>
__global__ void k_gather8(const float4* __restrict__ hs, const int* __restrict__ csr_row,
                          const int* __restrict__ off, const float* __restrict__ dinv,
                          float4* __restrict__ out) {
    constexpr int L = C / 4;
    constexpr int NPB = 256 / L;
    int local = threadIdx.x / L;
    int c4 = threadIdx.x % L;
    int n = blockIdx.x * NPB + local;
    int s = off[n], e = off[n + 1];
    float4 acc = hs[n * L + c4];      // self term
    int i = s;
    for (; i + 8 <= e; i += 8) {
        int r0 = csr_row[i + 0], r1 = csr_row[i + 1], r2 = csr_row[i + 2], r3 = csr_row[i + 3];
        int r4 = csr_row[i + 4], r5 = csr_row[i + 5], r6 = csr_row[i + 6], r7 = csr_row[i + 7];
        float4 a0 = hs[r0 * L + c4], a1 = hs[r1 * L + c4];
        float4 a2 = hs[r2 * L + c4], a3 = hs[r3 * L + c4];
        float4 a4 = hs[r4 * L + c4], a5 = hs[r5 * L + c4];
        float4 a6 = hs[r6 * L + c4], a7 = hs[r7 * L + c4];
        f4add(a0, a1); f4add(a2, a3); f4add(a4, a5); f4add(a6, a7);
        f4add(a0, a2); f4add(a4, a6);
        f4add(a0, a4);
        f4add(acc, a0);
    }
    for (; i < e; ++i) {
        int r = csr_row[i];
        float4 a = hs[r * L + c4];
        f4add(acc, a);
    }
    float dn = dinv[n];
    acc.x *= dn; acc.y *= dn; acc.z *= dn; acc.w *= dn;
    out[n * L + c4] = acc;
}

// ---------------- gather128 + bias + relu + fused run-based readout into gsum ----------------
__global__ void k_gather_ro(const float4* __restrict__ t2, const int* __restrict__ csr_row,
                            const int* __restrict__ off, const float* __restrict__ dinv,
                            const float* __restrict__ bias, const int* __restrict__ batch,
                            float* __restrict__ gsum) {
    constexpr int L = EMB / 4;        // 32
    constexpr int NPB = 8;
    __shared__ __align__(16) float hb[NPB][EMB];
    __shared__ int bg[NPB];
    int local = threadIdx.x >> 5;
    int c4 = threadIdx.x & 31;
    int n0 = blockIdx.x * NPB;
    int n = n0 + local;
    if (threadIdx.x < NPB) bg[threadIdx.x] = batch[n0 + threadIdx.x];
    int s = off[n], e = off[n + 1];
    float4 acc = t2[n * L + c4];      // self term
    int i = s;
    for (; i + 8 <= e; i += 8) {
        int r0 = csr_row[i + 0], r1 = csr_row[i + 1], r2 = csr_row[i + 2], r3 = csr_row[i + 3];
        int r4 = csr_row[i + 4], r5 = csr_row[i + 5], r6 = csr_row[i + 6], r7 = csr_row[i + 7];
        float4 a0 = t2[r0 * L + c4], a1 = t2[r1 * L + c4];
        float4 a2 = t2[r2 * L + c4], a3 = t2[r3 * L + c4];
        float4 a4 = t2[r4 * L + c4], a5 = t2[r5 * L + c4];
        float4 a6 = t2[r6 * L + c4], a7 = t2[r7 * L + c4];
        f4add(a0, a1); f4add(a2, a3); f4add(a4, a5); f4add(a6, a7);
        f4add(a0, a2); f4add(a4, a6);
        f4add(a0, a4);
        f4add(acc, a0);
    }
    for (; i < e; ++i) {
        int r = csr_row[i];
        float4 a = t2[r * L + c4];
        f4add(acc, a);
    }
    float dn = dinv[n];
    float4 b = reinterpret_cast<const float4*>(bias)[c4];
    acc.x = fmaxf(fmaf(acc.x, dn, b.x), 0.f);
    acc.y = fmaxf(fmaf(acc.y, dn, b.y), 0.f);
    acc.z = fmaxf(fmaf(acc.z, dn, b.z), 0.f);
    acc.w = fmaxf(fmaf(acc.w, dn, b.w), 0.f);
    *reinterpret_cast<float4*>(&hb[local][c4 * 4]) = acc;
    __syncthreads();
    int ch = threadIdx.x;
    if (ch < EMB) {
        int g = bg[0];
        float a = 0.f;
        #pragma unroll
        for (int j = 0; j < NPB; ++j) {
            int gj = bg[j];
            if (gj != g) { atomicAdd(&gsum[g * EMB + ch], a); a = 0.f; g = gj; }
            a += hb[j][ch];
        }
        atomicAdd(&gsum[g * EMB + ch], a);
    }
}

// ---------------- reg-blocked GEMM: 64 rows x 128 cols per block, 8x4 per thread ----------------
template <int K, bool RELU, bool BIAS, bool POSTSCALE>
__global__ void k_gemmv2(const float* __restrict__ A, const float* __restrict__ Wt,
                         const float* __restrict__ bias, const float* __restrict__ rowscale,
                         float* __restrict__ out) {
    int t = threadIdx.x;
    int cq = (t & 31) << 2;          // col base 0..124
    int rg = t >> 5;                 // 0..7
    int row0 = blockIdx.x * 64 + rg * 8;
    float4 acc[8];
    #pragma unroll
    for (int r = 0; r < 8; ++r) acc[r] = make_float4(0.f, 0.f, 0.f, 0.f);
    for (int k = 0; k < K; k += 4) {
        float4 w0 = *reinterpret_cast<const float4*>(&Wt[(k + 0) * EMB + cq]);
        float4 w1 = *reinterpret_cast<const float4*>(&Wt[(k + 1) * EMB + cq]);
        float4 w2 = *reinterpret_cast<const float4*>(&Wt[(k + 2) * EMB + cq]);
        float4 w3 = *reinterpret_cast<const float4*>(&Wt[(k + 3) * EMB + cq]);
        #pragma unroll
        for (int r = 0; r < 8; ++r) {
            float4 a = *reinterpret_cast<const float4*>(&A[(size_t)(row0 + r) * K + k]);
            acc[r].x = fmaf(a.x, w0.x, fmaf(a.y, w1.x, fmaf(a.z, w2.x, fmaf(a.w, w3.x, acc[r].x))));
            acc[r].y = fmaf(a.x, w0.y, fmaf(a.y, w1.y, fmaf(a.z, w2.y, fmaf(a.w, w3.y, acc[r].y))));
            acc[r].z = fmaf(a.x, w0.z, fmaf(a.y, w1.z, fmaf(a.z, w2.z, fmaf(a.w, w3.z, acc[r].z))));
            acc[r].w = fmaf(a.x, w0.w, fmaf(a.y, w1.w, fmaf(a.z, w2.w, fmaf(a.w, w3.w, acc[r].w))));
        }
    }
    #pragma unroll
    for (int r = 0; r < 8; ++r) {
        int row = row0 + r;
        if (row < N_NODES) {
            float4 v = acc[r];
            if (BIAS) {
                float4 b = *reinterpret_cast<const float4*>(&bias[cq]);
                v.x += b.x; v.y += b.y; v.z += b.z; v.w += b.w;
            }
            if (RELU) {
                v.x = fmaxf(v.x, 0.f); v.y = fmaxf(v.y, 0.f);
                v.z = fmaxf(v.z, 0.f); v.w = fmaxf(v.w, 0.f);
            }
            if (POSTSCALE) {
                float sc = rowscale[row];
                v.x *= sc; v.y *= sc; v.z *= sc; v.w *= sc;
            }
            *reinterpret_cast<float4*>(&out[(size_t)row * EMB + cq]) = v;
        }
    }
}

// ---------------- digitize: presence + exclusive scan, one block ----------------
__global__ void k_digitize(const int* __restrict__ dd, int* __restrict__ rankx) {
    __shared__ int pres[N_GRAPHS];
    __shared__ int ws[4];
    __shared__ int carry;
    int t = threadIdx.x, lane = t & 63, wid = t >> 6;
    for (int i = t; i < N_GRAPHS; i += 256) pres[i] = 0;
    __syncthreads();
    for (int i = t; i < 2 * N_PAIRS; i += 256) pres[dd[i]] = 1;
    if (t == 0) carry = 0;
    __syncthreads();
    for (int base = 0; base < N_GRAPHS; base += 256) {
        int i = base + t;
        int v = (i < N_GRAPHS) ? pres[i] : 0;
        int x = wave_incl_scan(v, lane);
        if (lane == 63) ws[wid] = x;
        __syncthreads();
        int add = carry;
        for (int w = 0; w < wid; ++w) add += ws[w];
        if (i < N_GRAPHS) rankx[i] = x - v + add;
        __syncthreads();
        if (t == 255) carry = add + x;
        __syncthreads();
    }
}

// ---------------- pair MLP, 16 pairs/block, mean-division fused at load ----------------
__global__ void k_mlp16(const float* __restrict__ gemb, const int* __restrict__ cnt,
                        const int* __restrict__ dd, const int* __restrict__ rankx,
                        const float* __restrict__ w1, const float* __restrict__ b1,
                        const float* __restrict__ w2, const float* __restrict__ b2,
                        float* __restrict__ out) {
    __shared__ __align__(16) float pv[PPB][2 * EMB];
    __shared__ float wpart[4][PPB];
    int p0 = blockIdx.x * PPB;
    int t = threadIdx.x;             // 0..255
    int lane = t & 63, wid = t >> 6;
    #pragma unroll
    for (int j = 0; j < PPB; ++j) {
        int p = p0 + j;
        if (t < EMB) {
            int ga = rankx[dd[p]];
            int ca = cnt[ga];
            float ra = 1.0f / (float)(ca > 1 ? ca : 1);
            pv[j][t] = gemb[ga * EMB + t] * ra;
        } else {
            int gb = rankx[dd[N_PAIRS + p]];
            int cb = cnt[gb];
            float rb = 1.0f / (float)(cb > 1 ? cb : 1);
            pv[j][t] = gemb[gb * EMB + (t - EMB)] * rb;
        }
    }
    __syncthreads();
    float acc[PPB];
    float bv = b1[t];
    #pragma unroll
    for (int j = 0; j < PPB; ++j) acc[j] = bv;
    const float4* wrow = reinterpret_cast<const float4*>(&w1[t * 2 * EMB]);
    for (int k = 0; k < (2 * EMB) / 4; ++k) {
        float4 w = wrow[k];
        #pragma unroll
        for (int j = 0; j < PPB; ++j) {
            const float4 xv = *reinterpret_cast<const float4*>(&pv[j][k * 4]);
            acc[j] = fmaf(xv.x, w.x, fmaf(xv.y, w.y, fmaf(xv.z, w.z, fmaf(xv.w, w.w, acc[j]))));
        }
    }
    float w2t = w2[t];
    float contrib[PPB];
    #pragma unroll
    for (int j = 0; j < PPB; ++j) contrib[j] = fmaxf(acc[j], 0.f) * w2t;
    #pragma unroll
    for (int off = 32; off > 0; off >>= 1) {
        #pragma unroll
        for (int j = 0; j < PPB; ++j) contrib[j] += __shfl_down(contrib[j], off, 64);
    }
    if (lane == 0) {
        #pragma unroll
        for (int j = 0; j < PPB; ++j) wpart[wid][j] = contrib[j];
    }
    __syncthreads();
    if (t < PPB) {
        out[p0 + t] = wpart[0][t] + wpart[1][t] + wpart[2][t] + wpart[3][t] + b2[0];
    }
}

extern "C" void kernel_launch(void* const* d_in, const int* in_sizes, int n_in,
                              void* d_out, int out_size, void* d_ws, size_t ws_size,
                              hipStream_t stream) {
    const float* x        = (const float*)d_in[0];
    const int*   ei       = (const int*)d_in[1];      // [2, E]
    const int*   batch    = (const int*)d_in[2];
    const int*   dd       = (const int*)d_in[3];      // [2, P]
    const float* conv1_w  = (const float*)d_in[4];
    const float* conv1_b  = (const float*)d_in[5];
    const float* conv2_w  = (const float*)d_in[6];
    const float* conv2_b  = (const float*)d_in[7];
    const float* reg1_w   = (const float*)d_in[8];
    const float* reg1_b   = (const float*)d_in[9];
    const float* reg2_w   = (const float*)d_in[10];
    const float* reg2_b   = (const float*)d_in[11];
    float* outp = (float*)d_out;

    const int* ei_row = ei;
    const int* ei_col = ei + N_EDGES;

    // ---- workspace layout ----
    char* ws = (char*)d_ws;
    size_t o = 0;
    auto alloc = [&](size_t bytes) -> void* {
        void* p = ws + o;
        o = (o + bytes + 255) & ~(size_t)255;
        return p;
    };
    size_t zero_start = o;
    int*   deg     = (int*)alloc(N_NODES * 4);
    int*   cnt     = (int*)alloc(N_GRAPHS * 4);
    float* gsum    = (float*)alloc(N_GRAPHS * EMB * 4);
    size_t zero_bytes = o - zero_start;
    int*   off     = (int*)alloc((N_NODES + 1) * 4);
    float* dinv    = (float*)alloc(N_NODES * 4);
    int*   part    = (int*)alloc(256 * 4);
    int*   pos_e   = (int*)alloc(N_EDGES * 4);
    int*   csr_row = (int*)alloc(N_EDGES * 4);
    int*   rankx   = (int*)alloc(N_GRAPHS * 4);
    float* Wt1     = (float*)alloc(IN_CH * EMB * 4);
    float* Wt2     = (float*)alloc(EMB * EMB * 4);
    float* aggx    = (float*)alloc((size_t)N_PAD * IN_CH * 4);
    float* h1s     = (float*)alloc((size_t)N_PAD * EMB * 4);
    float* t2      = (float*)alloc((size_t)N_PAD * EMB * 4);
    float* xs      = t2;   // xs (12.8MB) dead before GEMM2 writes t2

    (void)ws_size; (void)in_sizes; (void)n_in; (void)out_size;

    hipMemsetAsync(ws + zero_start, 0, zero_bytes, stream);

    // pre: deg + per-edge rank + graph counts + weight transposes
    k_pre<<<N_EDGES / 256, 256, 0, stream>>>(ei_col, batch, conv1_w, conv2_w,
                                             deg, pos_e, cnt, Wt1, Wt2);
    {
        int nb = (N_NODES + 255) / 256;   // 196
        k_scan1<<<nb, 256, 0, stream>>>(deg, part, N_NODES);
        k_scan2<<<1, 256, 0, stream>>>(part, nb);
        k_scan3d<<<nb, 256, 0, stream>>>(deg, part, off, dinv);
    }
    k_fill_scale<<<(N_EDGES + N_NODES * (IN_CH / 4)) / 256, 256, 0, stream>>>(
        ei_row, ei_col, pos_e, off, csr_row, (const float4*)x, dinv, (float4*)xs);

    // conv1: aggregate in 64-dim input space, then GEMM (+bias,relu, x dinv for conv2 prescale)
    k_gather8<IN_CH><<<N_NODES / (256 / (IN_CH / 4)), 256, 0, stream>>>(
        (const float4*)xs, csr_row, off, dinv, (float4*)aggx);
    k_gemmv2<IN_CH, true, true, true><<<N_PAD / 64, 256, 0, stream>>>(
        aggx, Wt1, conv1_b, dinv, h1s);

    // conv2: plain GEMM, then gather + bias + relu + fused readout
    k_gemmv2<EMB, false, false, false><<<N_PAD / 64, 256, 0, stream>>>(
        h1s, Wt2, nullptr, nullptr, t2);
    k_gather_ro<<<N_NODES / 8, 256, 0, stream>>>(
        (const float4*)t2, csr_row, off, dinv, conv2_b, batch, gsum);

    // digitize-rank (one block)
    k_digitize<<<1, 256, 0, stream>>>(dd, rankx);

    // pair MLP (mean division fused)
    k_mlp16<<<N_PAIRS / PPB, 256, 0, stream>>>(gsum, cnt, dd, rankx,
                                               reg1_w, reg1_b, reg2_w, reg2_b, outp);
}